// Round 4
// baseline (297.975 us; speedup 1.0000x reference)
//
#include <hip/hip_runtime.h>
#include <hip/hip_bf16.h>

typedef __attribute__((ext_vector_type(8))) short bf16x8;
typedef __attribute__((ext_vector_type(4))) float f32x4;
typedef unsigned short u16;
typedef unsigned int u32;

#define B_ 2
#define S_ 2048
#define E_ 2048
#define H_ 16
#define DK_ 128
#define SCALE_ 0.08838834764831845f  // 1/sqrt(128)
#define THR_RAW_ 90.5f               // defer-max threshold: 8 / SCALE_

#define MFMA16(a,b,c) __builtin_amdgcn_mfma_f32_16x16x32_bf16((a),(b),(c),0,0,0)
#define GLD16(g, l) __builtin_amdgcn_global_load_lds((const __attribute__((address_space(1))) void*)(g), (__attribute__((address_space(3))) void*)(l), 16, 0, 0)

__device__ __forceinline__ float b2f(short s) {
    u32 u = ((u32)(u16)s) << 16;
    float f; __builtin_memcpy(&f, &u, 4); return f;
}

// ---------------- cast f32 -> bf16 (vectorized x4) ----------------
__global__ void cast_f32_bf16(const float* __restrict__ in, __hip_bfloat16* __restrict__ out, int n4) {
    int i = blockIdx.x * blockDim.x + threadIdx.x;
    if (i >= n4) return;
    float4 v = ((const float4*)in)[i];
    __hip_bfloat16 ob[4] = {__float2bfloat16(v.x), __float2bfloat16(v.y),
                            __float2bfloat16(v.z), __float2bfloat16(v.w)};
    ushort4 u; __builtin_memcpy(&u, ob, 8);
    ((ushort4*)out)[i] = u;
}

// 4 weights in one launch (blockIdx.y selects tensor)
__global__ void cast_w4(const float* __restrict__ w0, const float* __restrict__ w1,
                        const float* __restrict__ w2, const float* __restrict__ w3,
                        __hip_bfloat16* __restrict__ o0, __hip_bfloat16* __restrict__ o1,
                        __hip_bfloat16* __restrict__ o2, __hip_bfloat16* __restrict__ o3,
                        int n4) {
    int i = blockIdx.x * blockDim.x + threadIdx.x;
    if (i >= n4) return;
    const float* in = blockIdx.y == 0 ? w0 : blockIdx.y == 1 ? w1 : blockIdx.y == 2 ? w2 : w3;
    __hip_bfloat16* out = blockIdx.y == 0 ? o0 : blockIdx.y == 1 ? o1 : blockIdx.y == 2 ? o2 : o3;
    float4 v = ((const float4*)in)[i];
    __hip_bfloat16 ob[4] = {__float2bfloat16(v.x), __float2bfloat16(v.y),
                            __float2bfloat16(v.z), __float2bfloat16(v.w)};
    ushort4 u; __builtin_memcpy(&u, ob, 8);
    ((ushort4*)out)[i] = u;
}

// ---------------- trig table: ct/st[s][d2] = cos/sin(pe[s][2*d2]) ----------------
__global__ void trig_table(const float* __restrict__ pe, float* __restrict__ ct,
                           float* __restrict__ st) {
    int t = blockIdx.x * blockDim.x + threadIdx.x;   // 0 .. S*64-1
    int s = t >> 6, d2 = t & 63;
    float ang = pe[(size_t)s * DK_ + 2 * d2];
    ct[t] = cosf(ang);
    st[t] = sinf(ang);
}

// ================= fused QKV projection: 256x256 tile, BK=64, 8-phase pipeline ============
// 8 waves (2M x 4N), per-wave C = 128x64 (acc[8][4] of 16x16 frags).
// LDS: A/B double-buffered [2][256][64] bf16 (128 KB). XOR swizzle byte^=(row&7)<<4.
// Schedule per K-tile t (buf=t&1), 4 phases = C-quadrants (mh,nh)=(0,0),(0,1),(1,0),(1,1):
//   P0 stages t+1's A rows {64-127,192-255} (buf^1, free since t-1 ended)
//   P1 stages t+1's B nh=1 stripes          (buf^1)
//   P2 stages t+2's A rows {0-63,128-191}   (buf, freed: mh=0 last read at P1)
//   P3 stages t+2's B nh=0 stripes          (buf, freed: nh=0 last read at P2)
//   boundary: vmcnt(4) -> drains ALL of t+1, leaves t+2's 4 early loads in flight.
// Raw s_barrier throughout (no __syncthreads: it would drain vmcnt(0) and kill the pipe).

#define STAGE_A8(BUF, MH, KB) do { \
    _Pragma("unroll") for (int cc_ = 0; cc_ < 2; ++cc_) { \
        int row_ = cc_*128 + (MH)*64 + (tid>>3); \
        int gc_ = ((tid&7)*16) ^ ((row_&7)<<4); \
        GLD16(Ab + (size_t)(m0+row_)*K2 + (KB) + gc_, \
              (char*)As[BUF] + (cc_*128 + (MH)*64)*128 + tid*16); \
    } } while (0)

#define STAGE_B8(BUF, NH, KB) do { \
    _Pragma("unroll") for (int cc_ = 0; cc_ < 2; ++cc_) { \
        int rg_ = cc_*128 + ((tid>>8)<<6) + (NH)*32; \
        int row_ = rg_ + ((tid&255)>>3); \
        int gc_ = ((tid&7)*16) ^ ((row_&7)<<4); \
        GLD16(Wb + (size_t)(n0+row_)*K2 + (KB) + gc_, \
              (char*)Bs[BUF] + rg_*128 + (tid&255)*16); \
    } } while (0)

#define PHASE8(BUF, MH, NH, STAGE_STMT, TAIL_STMT) do { \
    bf16x8 af_[4][2], bf_[2][2]; \
    _Pragma("unroll") for (int i_ = 0; i_ < 4; ++i_) { \
        int ar_ = wm*128 + ((MH)*4+i_)*16 + c; \
        const char* ab_ = (const char*)As[BUF] + ar_*128; \
        _Pragma("unroll") for (int ks_ = 0; ks_ < 2; ++ks_) \
            af_[i_][ks_] = *(const bf16x8*)(ab_ + ((ks_*64 + g*16) ^ ((ar_&7)<<4))); \
    } \
    _Pragma("unroll") for (int j_ = 0; j_ < 2; ++j_) { \
        int br_ = wn*64 + ((NH)*2+j_)*16 + c; \
        const char* bb_ = (const char*)Bs[BUF] + br_*128; \
        _Pragma("unroll") for (int ks_ = 0; ks_ < 2; ++ks_) \
            bf_[j_][ks_] = *(const bf16x8*)(bb_ + ((ks_*64 + g*16) ^ ((br_&7)<<4))); \
    } \
    STAGE_STMT; \
    __builtin_amdgcn_s_barrier(); \
    asm volatile("s_waitcnt lgkmcnt(0)" ::: "memory"); \
    __builtin_amdgcn_sched_barrier(0); \
    __builtin_amdgcn_s_setprio(1); \
    _Pragma("unroll") for (int i_ = 0; i_ < 4; ++i_) \
        _Pragma("unroll") for (int j_ = 0; j_ < 2; ++j_) \
            _Pragma("unroll") for (int ks_ = 0; ks_ < 2; ++ks_) \
                acc[(MH)*4+i_][(NH)*2+j_] = MFMA16(af_[i_][ks_], bf_[j_][ks_], acc[(MH)*4+i_][(NH)*2+j_]); \
    __builtin_amdgcn_s_setprio(0); \
    TAIL_STMT; \
    __builtin_amdgcn_s_barrier(); \
} while (0)

__global__ __launch_bounds__(512, 2)
void gemm_qkv8(const __hip_bfloat16* __restrict__ X,
               const __hip_bfloat16* __restrict__ WQ, const __hip_bfloat16* __restrict__ WK,
               const __hip_bfloat16* __restrict__ WV,
               __hip_bfloat16* __restrict__ Qo, __hip_bfloat16* __restrict__ Ko,
               __hip_bfloat16* __restrict__ Vo,
               const float* __restrict__ CT, const float* __restrict__ ST)
{
    __shared__ __align__(16) __hip_bfloat16 As[2][256 * 64];
    __shared__ __align__(16) __hip_bfloat16 Bs[2][256 * 64];
    const int tid = threadIdx.x, lane = tid & 63, wid = tid >> 6;
    const int wm = wid >> 2, wn = wid & 3;
    const int g = (lane >> 4), c = lane & 15;
    const int which = blockIdx.y >> 3;
    const __hip_bfloat16* W = which == 0 ? WQ : which == 1 ? WK : WV;
    const int m0 = blockIdx.x * 256, n0 = (blockIdx.y & 7) * 256;
    const long K2 = E_ * 2;   // row stride bytes
    const char* Ab = (const char*)X;
    const char* Wb = (const char*)W;

    f32x4 acc[8][4];
    #pragma unroll
    for (int i = 0; i < 8; ++i)
        #pragma unroll
        for (int j = 0; j < 4; ++j) acc[i][j] = f32x4{0.f, 0.f, 0.f, 0.f};

    // prologue: T0 fully, then T1's early halves; drain T0, keep T1-early in flight
    STAGE_A8(0, 0, 0);  STAGE_B8(0, 0, 0);
    STAGE_A8(0, 1, 0);  STAGE_B8(0, 1, 0);
    STAGE_A8(1, 0, 128); STAGE_B8(1, 0, 128);
    asm volatile("s_waitcnt vmcnt(4)" ::: "memory");
    __builtin_amdgcn_s_barrier();

    for (int t = 0; t < 32; ++t) {
        const int buf = t & 1;
        const long kb1 = (long)(t + 1) * 128;
        const long kb2 = (long)(t + 2) * 128;
        PHASE8(buf, 0, 0, { if (t < 31) STAGE_A8(buf ^ 1, 1, kb1); }, {});
        PHASE8(buf, 0, 1, { if (t < 31) STAGE_B8(buf ^ 1, 1, kb1); }, {});
        PHASE8(buf, 1, 0, { if (t < 30) STAGE_A8(buf, 0, kb2); }, {});
        PHASE8(buf, 1, 1, { if (t < 30) STAGE_B8(buf, 0, kb2); },
               { if (t < 30) { asm volatile("s_waitcnt vmcnt(4)" ::: "memory"); }
                 else if (t == 30) { asm volatile("s_waitcnt vmcnt(0)" ::: "memory"); } });
    }

    // epilogue
    if (which < 2) {
        __hip_bfloat16* Cq = which == 0 ? Qo : Ko;
        #pragma unroll
        for (int mi = 0; mi < 8; ++mi)
            #pragma unroll
            for (int nj = 0; nj < 4; ++nj)
                #pragma unroll
                for (int r = 0; r < 4; ++r) {
                    float v = acc[mi][nj][r];
                    float vp = __shfl_xor(v, 1);   // partner d^1 (c parity == d parity)
                    int m = m0 + wm * 128 + mi * 16 + 4 * g + r;
                    int n = n0 + wn * 64 + nj * 16 + c;
                    int srow = m & (S_ - 1), d = n & (DK_ - 1);
                    float cs = CT[srow * 64 + (d >> 1)];
                    float sn = ST[srow * 64 + (d >> 1)];
                    float o = (c & 1) ? __builtin_fmaf(v, cs, vp * sn)
                                      : __builtin_fmaf(v, cs, -vp * sn);
                    size_t a = ((size_t)((m >> 11) * 16 + (n >> 7)) * S_ + srow) * DK_ + d;
                    Cq[a] = __float2bfloat16(o);
                }
    } else {
        #pragma unroll
        for (int mi = 0; mi < 8; ++mi)
            #pragma unroll
            for (int nj = 0; nj < 4; ++nj) {
                int m = m0 + wm * 128 + mi * 16 + 4 * g;   // r=0 row
                int n = n0 + wn * 64 + nj * 16 + c;
                int s0 = m & (S_ - 1), d = n & (DK_ - 1);
                __hip_bfloat16 ob[4];
                #pragma unroll
                for (int r = 0; r < 4; ++r) ob[r] = __float2bfloat16(acc[mi][nj][r]);
                ushort4 u; __builtin_memcpy(&u, ob, 8);
                size_t a = ((size_t)((m >> 11) * 16 + (n >> 7)) * DK_ + d) * S_ + s0;
                *(ushort4*)(Vo + a) = u;
            }
    }
}

// ---------------- out-projection GEMM (f32 out), 128x128 2-phase ----------------
__global__ __launch_bounds__(256, 2)
void gemm_out(const __hip_bfloat16* __restrict__ A, const __hip_bfloat16* __restrict__ W,
              float* __restrict__ Cout, int M, int N, int K)
{
    __shared__ __align__(16) __hip_bfloat16 As[128 * 64];
    __shared__ __align__(16) __hip_bfloat16 Bs[128 * 64];
    const int tid = threadIdx.x;
    const int lane = tid & 63, wv = tid >> 6;
    const int wr = wv >> 1, wc = wv & 1;
    const int m0 = blockIdx.x * 128, n0 = blockIdx.y * 128;
    const int g = lane >> 4, c = lane & 15;

    f32x4 acc[4][4];
    #pragma unroll
    for (int i = 0; i < 4; ++i)
        #pragma unroll
        for (int j = 0; j < 4; ++j) acc[i][j] = f32x4{0.f, 0.f, 0.f, 0.f};

    for (int k0 = 0; k0 < K; k0 += 64) {
        __syncthreads();
        #pragma unroll
        for (int it = 0; it < 4; ++it) {
            int o = (it * 256 + tid) * 16;
            int row = o >> 7;
            int colb = (o ^ ((row & 7) << 4)) & 127;
            GLD16((const char*)(A + (size_t)(m0 + row) * K + k0) + colb, (char*)As + o);
            GLD16((const char*)(W + (size_t)(n0 + row) * K + k0) + colb, (char*)Bs + o);
        }
        __syncthreads();
        #pragma unroll
        for (int ks = 0; ks < 2; ++ks) {
            bf16x8 af[4], bfm[4];
            #pragma unroll
            for (int i = 0; i < 4; ++i) {
                int arow = wr * 64 + i * 16 + c;
                int ab = arow * 128 + ((ks * 64 + g * 16) ^ ((arow & 7) << 4));
                af[i] = *(const bf16x8*)((const char*)As + ab);
                int brow = wc * 64 + i * 16 + c;
                int bb = brow * 128 + ((ks * 64 + g * 16) ^ ((brow & 7) << 4));
                bfm[i] = *(const bf16x8*)((const char*)Bs + bb);
            }
            #pragma unroll
            for (int i = 0; i < 4; ++i)
                #pragma unroll
                for (int j = 0; j < 4; ++j)
                    acc[i][j] = MFMA16(af[i], bfm[j], acc[i][j]);
        }
    }

    #pragma unroll
    for (int i = 0; i < 4; ++i)
        #pragma unroll
        for (int j = 0; j < 4; ++j)
            #pragma unroll
            for (int r = 0; r < 4; ++r) {
                int m = m0 + wr * 64 + i * 16 + 4 * g + r;
                int n = n0 + wc * 64 + j * 16 + c;
                Cout[(size_t)m * N + n] = acc[i][j][r];
            }
}

// ---------------- flash attention (causal), XCD-swizzled + balanced pairs ---------
__device__ __forceinline__ void stage_kv(const __hip_bfloat16* Kp, const __hip_bfloat16* Vp,
                                         char* ks, char* vs, int kv0, int tid) {
    #pragma unroll
    for (int it = 0; it < 4; ++it) {  // K tile: [64][128] bf16, 256B rows
        int o = (it * 256 + tid) * 16;
        int row = o >> 8;
        int cb = (o ^ ((row & 7) << 4)) & 255;
        GLD16((const char*)(Kp + (size_t)(kv0 + row) * DK_) + cb, ks + o);
    }
    #pragma unroll
    for (int it = 0; it < 4; ++it) {  // V^T tile: [128][64] bf16, 128B rows
        int o = (it * 256 + tid) * 16;
        int row = o >> 7;
        int cb = (o ^ ((row & 7) << 4)) & 127;
        GLD16((const char*)(Vp + (size_t)row * S_ + kv0) + cb, vs + o);
    }
}

__global__ __launch_bounds__(256, 2)
void attn_kernel(const __hip_bfloat16* __restrict__ Q,   // (B,H,S,DK) roped
                 const __hip_bfloat16* __restrict__ Kt,  // (B,H,S,DK) roped
                 const __hip_bfloat16* __restrict__ VT,  // (B,H,DK,S)
                 __hip_bfloat16* __restrict__ O)         // (B,S,H*DK)
{
    __shared__ __align__(16) __hip_bfloat16 Ks[2][64 * 128];
    __shared__ __align__(16) __hip_bfloat16 Vs[2][128 * 64];
    __shared__ __align__(16) __hip_bfloat16 Ps[4][16 * 72];

    const int tid = threadIdx.x, lane = tid & 63, w = tid >> 6;
    const int g = lane >> 4, c = lane & 15;
    const int id = blockIdx.x;
    const int slot = id & 7, jj = id >> 3;
    const int bh = ((jj >> 4) << 3) | slot;
    const int xq = jj & 15;
    const int b = bh >> 4, h = bh & 15;
    const size_t base_bh = (size_t)bh * S_ * DK_;
    const __hip_bfloat16* Qp = Q + base_bh;
    const __hip_bfloat16* Kp = Kt + base_bh;
    const __hip_bfloat16* Vp = VT + base_bh;

    #pragma unroll 1
    for (int pass = 0; pass < 2; ++pass) {
        const int qt = pass ? (31 - xq) : xq;
        const int qw = qt * 64 + w * 16;
        const int ntiles = qt + 1;

        bf16x8 qf[4];
        #pragma unroll
        for (int ds = 0; ds < 4; ++ds)
            qf[ds] = *(const bf16x8*)(Qp + (size_t)(qw + c) * DK_ + ds * 32 + g * 8);

        f32x4 oacc[8];
        #pragma unroll
        for (int fd = 0; fd < 8; ++fd) oacc[fd] = f32x4{0.f, 0.f, 0.f, 0.f};
        float M[4], L[4];
        #pragma unroll
        for (int r = 0; r < 4; ++r) { M[r] = -1e30f; L[r] = 0.f; }

        stage_kv(Kp, Vp, (char*)Ks[0], (char*)Vs[0], 0, tid);
        __syncthreads();

        int cur = 0;
        for (int t = 0; t < ntiles; ++t) {
            const int kv0 = t * 64;
            if (t + 1 < ntiles)
                stage_kv(Kp, Vp, (char*)Ks[cur ^ 1], (char*)Vs[cur ^ 1], kv0 + 64, tid);

            const bool diag = (kv0 + 63 > qw);

            f32x4 sacc[4];
            #pragma unroll
            for (int f = 0; f < 4; ++f) sacc[f] = f32x4{0.f, 0.f, 0.f, 0.f};
            #pragma unroll
            for (int f = 0; f < 4; ++f) {
                #pragma unroll
                for (int ds = 0; ds < 4; ++ds) {
                    int krow = f * 16 + c;
                    int kbyt = krow * 256 + ((ds * 64 + g * 16) ^ ((krow & 7) << 4));
                    bf16x8 kf = *(const bf16x8*)((const char*)Ks[cur] + kbyt);
                    sacc[f] = MFMA16(qf[ds], kf, sacc[f]);
                }
            }

            float p[4][4];
            float mt[4] = {-1e30f, -1e30f, -1e30f, -1e30f};
            #pragma unroll
            for (int f = 0; f < 4; ++f)
                #pragma unroll
                for (int r = 0; r < 4; ++r) {
                    float v = sacc[f][r];
                    if (diag && (kv0 + f * 16 + c > qw + 4 * g + r)) v = -1e30f;
                    p[f][r] = v;
                    mt[r] = fmaxf(mt[r], v);
                }
            #pragma unroll
            for (int r = 0; r < 4; ++r) {
                float v = mt[r];
                v = fmaxf(v, __shfl_xor(v, 1));
                v = fmaxf(v, __shfl_xor(v, 2));
                v = fmaxf(v, __shfl_xor(v, 4));
                v = fmaxf(v, __shfl_xor(v, 8));
                mt[r] = v;
            }
            bool grow = (mt[0] > M[0] + THR_RAW_) || (mt[1] > M[1] + THR_RAW_) ||
                        (mt[2] > M[2] + THR_RAW_) || (mt[3] > M[3] + THR_RAW_);
            if (__any(grow)) {
                float al[4];
                #pragma unroll
                for (int r = 0; r < 4; ++r) {
                    float mn = fmaxf(M[r], mt[r]);
                    al[r] = __expf((M[r] - mn) * SCALE_);
                    M[r] = mn;
                    L[r] *= al[r];
                }
                #pragma unroll
                for (int fd = 0; fd < 8; ++fd)
                    #pragma unroll
                    for (int r = 0; r < 4; ++r) oacc[fd][r] *= al[r];
            }
            float ms[4];
            #pragma unroll
            for (int r = 0; r < 4; ++r) ms[r] = M[r] * SCALE_;
            float lt[4] = {0.f, 0.f, 0.f, 0.f};
            #pragma unroll
            for (int f = 0; f < 4; ++f)
                #pragma unroll
                for (int r = 0; r < 4; ++r) {
                    float e = __expf(__builtin_fmaf(p[f][r], SCALE_, -ms[r]));
                    lt[r] += e;
                    Ps[w][(4 * g + r) * 72 + f * 16 + c] = __float2bfloat16(e);
                }
            #pragma unroll
            for (int r = 0; r < 4; ++r) {
                float v = lt[r];
                v += __shfl_xor(v, 1);
                v += __shfl_xor(v, 2);
                v += __shfl_xor(v, 4);
                v += __shfl_xor(v, 8);
                L[r] += v;
            }

            #pragma unroll
            for (int ks2 = 0; ks2 < 2; ++ks2) {
                bf16x8 pf = *(const bf16x8*)&Ps[w][c * 72 + ks2 * 32 + g * 8];
                #pragma unroll
                for (int fd = 0; fd < 8; ++fd) {
                    int vrow = fd * 16 + c;
                    int vb = vrow * 128 + ((ks2 * 64 + g * 16) ^ ((vrow & 7) << 4));
                    bf16x8 vf = *(const bf16x8*)((const char*)Vs[cur] + vb);
                    oacc[fd] = MFMA16(pf, vf, oacc[fd]);
                }
            }
            __syncthreads();
            cur ^= 1;
        }

        float rl[4];
        #pragma unroll
        for (int r = 0; r < 4; ++r) rl[r] = 1.0f / L[r];
        #pragma unroll
        for (int fd = 0; fd < 8; ++fd) {
            #pragma unroll
            for (int r = 0; r < 4; ++r) {
                int s = qw + 4 * g + r;
                size_t a = ((size_t)(b * S_ + s)) * (H_ * DK_) + h * DK_ + fd * 16 + c;
                O[a] = __float2bfloat16(oacc[fd][r] * rl[r]);
            }
        }
    }
}

extern "C" void kernel_launch(void* const* d_in, const int* in_sizes, int n_in,
                              void* d_out, int out_size, void* d_ws, size_t ws_size,
                              hipStream_t stream) {
    const float* x  = (const float*)d_in[0];
    const float* wq = (const float*)d_in[1];
    const float* wk = (const float*)d_in[2];
    const float* wv = (const float*)d_in[3];
    const float* wo = (const float*)d_in[4];
    const float* pe = (const float*)d_in[5];
    float* out = (float*)d_out;

    const size_t XE = (size_t)B_ * S_ * E_;   // 8388608
    const size_t WE = (size_t)E_ * H_ * DK_;  // 4194304
    __hip_bfloat16* xb  = (__hip_bfloat16*)d_ws;
    __hip_bfloat16* wqb = xb + XE;
    __hip_bfloat16* wkb = wqb + WE;
    __hip_bfloat16* wvb = wkb + WE;
    __hip_bfloat16* wob = wvb + WE;
    __hip_bfloat16* qb  = wob + WE;  // (B,H,S,DK)
    __hip_bfloat16* kb  = qb + XE;   // (B,H,S,DK)
    __hip_bfloat16* vT  = kb + XE;   // (B,H,DK,S)
    __hip_bfloat16* at  = vT + XE;   // (B*S, H*DK)
    float* ct = (float*)(at + XE);   // cos table S*64
    float* st = ct + (size_t)S_ * 64;

    cast_f32_bf16<<<dim3((int)(XE / 4 / 256)), 256, 0, stream>>>(x, xb, (int)(XE / 4));
    cast_w4<<<dim3((int)(WE / 4 / 256), 4), 256, 0, stream>>>(wq, wk, wv, wo,
                                                              wqb, wkb, wvb, wob,
                                                              (int)(WE / 4));
    trig_table<<<dim3(S_ * 64 / 256), 256, 0, stream>>>(pe, ct, st);

    gemm_qkv8<<<dim3(16, 24), 512, 0, stream>>>(xb, wqb, wkb, wvb, qb, kb, vT, ct, st);

    attn_kernel<<<dim3(512), 256, 0, stream>>>(qb, kb, vT, at);

    gemm_out<<<dim3(32, 16), 256, 0, stream>>>(at, wob, out, B_ * S_, E_, H_ * DK_);
}

// Round 5
// 267.635 us; speedup vs baseline: 1.1134x; 1.1134x over previous
//
#include <hip/hip_runtime.h>
#include <hip/hip_bf16.h>

typedef __attribute__((ext_vector_type(8))) short bf16x8;
typedef __attribute__((ext_vector_type(4))) float f32x4;
typedef unsigned short u16;
typedef unsigned int u32;

#define B_ 2
#define S_ 2048
#define E_ 2048
#define H_ 16
#define DK_ 128
#define SCALE_ 0.08838834764831845f  // 1/sqrt(128)
#define THR_RAW_ 90.5f               // defer-max threshold: 8 / SCALE_

#define MFMA16(a,b,c) __builtin_amdgcn_mfma_f32_16x16x32_bf16((a),(b),(c),0,0,0)
#define GLD16(g, l) __builtin_amdgcn_global_load_lds((const __attribute__((address_space(1))) void*)(g), (__attribute__((address_space(3))) void*)(l), 16, 0, 0)

__device__ __forceinline__ float b2f(short s) {
    u32 u = ((u32)(u16)s) << 16;
    float f; __builtin_memcpy(&f, &u, 4); return f;
}

// ---------------- cast f32 -> bf16 (vectorized x4) ----------------
__global__ void cast_f32_bf16(const float* __restrict__ in, __hip_bfloat16* __restrict__ out, int n4) {
    int i = blockIdx.x * blockDim.x + threadIdx.x;
    if (i >= n4) return;
    float4 v = ((const float4*)in)[i];
    __hip_bfloat16 ob[4] = {__float2bfloat16(v.x), __float2bfloat16(v.y),
                            __float2bfloat16(v.z), __float2bfloat16(v.w)};
    ushort4 u; __builtin_memcpy(&u, ob, 8);
    ((ushort4*)out)[i] = u;
}

__global__ void cast_w4(const float* __restrict__ w0, const float* __restrict__ w1,
                        const float* __restrict__ w2, const float* __restrict__ w3,
                        __hip_bfloat16* __restrict__ o0, __hip_bfloat16* __restrict__ o1,
                        __hip_bfloat16* __restrict__ o2, __hip_bfloat16* __restrict__ o3,
                        int n4) {
    int i = blockIdx.x * blockDim.x + threadIdx.x;
    if (i >= n4) return;
    const float* in = blockIdx.y == 0 ? w0 : blockIdx.y == 1 ? w1 : blockIdx.y == 2 ? w2 : w3;
    __hip_bfloat16* out = blockIdx.y == 0 ? o0 : blockIdx.y == 1 ? o1 : blockIdx.y == 2 ? o2 : o3;
    float4 v = ((const float4*)in)[i];
    __hip_bfloat16 ob[4] = {__float2bfloat16(v.x), __float2bfloat16(v.y),
                            __float2bfloat16(v.z), __float2bfloat16(v.w)};
    ushort4 u; __builtin_memcpy(&u, ob, 8);
    ((ushort4*)out)[i] = u;
}

// ---------------- trig table ----------------
__global__ void trig_table(const float* __restrict__ pe, float* __restrict__ ct,
                           float* __restrict__ st) {
    int t = blockIdx.x * blockDim.x + threadIdx.x;
    int s = t >> 6, d2 = t & 63;
    float ang = pe[(size_t)s * DK_ + 2 * d2];
    ct[t] = cosf(ang);
    st[t] = sinf(ang);
}

// ================= fused QKV: 256x192 tile, BK=64, 4-phase pipeline + frag reuse ========
// 8 waves (2M x 4N), wave tile 128x48, acc[8][3]. LDS 112KB dbuf. W = concat(wq;wk;wv).
// Phases/K-tile: P0 {read A-MH0(8)+B-nj01(4), stage B(t+1)x3, 16 MFMA}
//                P1 {read B-nj2(2), stage A-early(t+1)x2, 8 MFMA, vmcnt(5)}
//                P2 {read A-MH1(8), stage A-late(t+1)x2, 16 MFMA}
//                P3 {8 MFMA, vmcnt(2)}       -- counted waits, never 0 mid-loop.
// vmcnt ledger (per thread): enter tile with 2 (A-late of this tile) in flight;
// +3 (P0) +2 (P1) =7 -> vmcnt(5) drains the 2 oldest (A-late of t) before P2 reads;
// +2 (P2) =7 -> boundary vmcnt(2) drains B+A-early of t+1, leaves its A-late. Each
// vmcnt sits BEFORE a closing s_barrier so the drain is block-global for the readers.

#define ST_B(BUF, Q, KB) do { \
    int row_ = (Q) * 64 + (tid >> 3); \
    int gc_ = ((tid & 7) * 16) ^ ((row_ & 7) << 4); \
    GLD16(Wb + (size_t)(n0 + row_) * K2 + (KB) + gc_, (char*)Bs[BUF] + (Q) * 8192 + tid * 16); \
} while (0)

#define ST_A(BUF, Q, KB) do { \
    int row_ = (Q) * 64 + (tid >> 3); \
    int gc_ = ((tid & 7) * 16) ^ ((row_ & 7) << 4); \
    GLD16(Ab + (size_t)(m0 + row_) * K2 + (KB) + gc_, (char*)As[BUF] + (Q) * 8192 + tid * 16); \
} while (0)

#define WAIT_MFMA_ENTER() do { \
    __builtin_amdgcn_s_barrier(); \
    asm volatile("s_waitcnt lgkmcnt(0)" ::: "memory"); \
    __builtin_amdgcn_sched_barrier(0); \
    __builtin_amdgcn_s_setprio(1); \
} while (0)

__global__ __launch_bounds__(512, 2)
void gemm_qkv8(const __hip_bfloat16* __restrict__ X,
               const __hip_bfloat16* __restrict__ Wcat,
               __hip_bfloat16* __restrict__ Qo, __hip_bfloat16* __restrict__ Ko,
               __hip_bfloat16* __restrict__ Vo,
               const float* __restrict__ CT, const float* __restrict__ ST)
{
    __shared__ __align__(16) __hip_bfloat16 As[2][256 * 64];
    __shared__ __align__(16) __hip_bfloat16 Bs[2][192 * 64];
    const int tid = threadIdx.x, lane = tid & 63, wid = tid >> 6;
    const int wm = wid >> 2, wn = wid & 3;
    const int g = lane >> 4, c = lane & 15;
    const int raw = blockIdx.x;
    const int wg = (raw & 7) * 64 + (raw >> 3);      // XCD-chunked, bijective (512 = 8*64)
    const int mtile = wg & 15, ntile = wg >> 4;
    const int m0 = mtile * 256, n0 = ntile * 192;
    const long K2 = E_ * 2;
    const char* Ab = (const char*)X;
    const char* Wb = (const char*)Wcat;

    f32x4 acc[8][3];
    #pragma unroll
    for (int i = 0; i < 8; ++i)
        #pragma unroll
        for (int j = 0; j < 3; ++j) acc[i][j] = f32x4{0.f, 0.f, 0.f, 0.f};

    bf16x8 af[4][2], b01[2][2], b2[2];

    // prologue: stage tile 0 in the ledger's issue order
    ST_B(0, 0, 0); ST_B(0, 1, 0); ST_B(0, 2, 0);
    ST_A(0, 0, 0); ST_A(0, 2, 0);
    ST_A(0, 1, 0); ST_A(0, 3, 0);
    asm volatile("s_waitcnt vmcnt(2)" ::: "memory");
    __builtin_amdgcn_s_barrier();

    #pragma unroll 1
    for (int t = 0; t < 32; ++t) {
        const int buf = t & 1;
        const long kb1 = (long)(t + 1) * 128;
        const char* Ac = (const char*)As[buf];
        const char* Bc = (const char*)Bs[buf];

        // ---- P0: A-MH0 + B-nj01 reads; stage B(t+1); MFMA quadrant (MH0, nj01)
        #pragma unroll
        for (int i = 0; i < 4; ++i) {
            int ar = wm * 128 + i * 16 + c;
            const char* ab = Ac + ar * 128;
            af[i][0] = *(const bf16x8*)(ab + ((g * 16) ^ ((ar & 7) << 4)));
            af[i][1] = *(const bf16x8*)(ab + ((64 + g * 16) ^ ((ar & 7) << 4)));
        }
        #pragma unroll
        for (int nj = 0; nj < 2; ++nj) {
            int br = wn * 48 + nj * 16 + c;
            const char* bb = Bc + br * 128;
            b01[nj][0] = *(const bf16x8*)(bb + ((g * 16) ^ ((br & 7) << 4)));
            b01[nj][1] = *(const bf16x8*)(bb + ((64 + g * 16) ^ ((br & 7) << 4)));
        }
        if (t < 31) { ST_B(buf ^ 1, 0, kb1); ST_B(buf ^ 1, 1, kb1); ST_B(buf ^ 1, 2, kb1); }
        WAIT_MFMA_ENTER();
        #pragma unroll
        for (int i = 0; i < 4; ++i)
            #pragma unroll
            for (int nj = 0; nj < 2; ++nj)
                #pragma unroll
                for (int k = 0; k < 2; ++k)
                    acc[i][nj] = MFMA16(af[i][k], b01[nj][k], acc[i][nj]);
        __builtin_amdgcn_s_setprio(0);
        __builtin_amdgcn_s_barrier();

        // ---- P1: B-nj2 reads; stage A-early(t+1); MFMA (MH0, nj2); vmcnt(5)
        {
            int br = wn * 48 + 32 + c;
            const char* bb = Bc + br * 128;
            b2[0] = *(const bf16x8*)(bb + ((g * 16) ^ ((br & 7) << 4)));
            b2[1] = *(const bf16x8*)(bb + ((64 + g * 16) ^ ((br & 7) << 4)));
        }
        if (t < 31) { ST_A(buf ^ 1, 0, kb1); ST_A(buf ^ 1, 2, kb1); }
        WAIT_MFMA_ENTER();
        #pragma unroll
        for (int i = 0; i < 4; ++i)
            #pragma unroll
            for (int k = 0; k < 2; ++k)
                acc[i][2] = MFMA16(af[i][k], b2[k], acc[i][2]);
        __builtin_amdgcn_s_setprio(0);
        if (t < 31) { asm volatile("s_waitcnt vmcnt(5)" ::: "memory"); }
        else        { asm volatile("s_waitcnt vmcnt(0)" ::: "memory"); }
        __builtin_amdgcn_s_barrier();

        // ---- P2: A-MH1 reads; stage A-late(t+1); MFMA (MH1, nj01)
        #pragma unroll
        for (int i = 0; i < 4; ++i) {
            int ar = wm * 128 + 64 + i * 16 + c;
            const char* ab = Ac + ar * 128;
            af[i][0] = *(const bf16x8*)(ab + ((g * 16) ^ ((ar & 7) << 4)));
            af[i][1] = *(const bf16x8*)(ab + ((64 + g * 16) ^ ((ar & 7) << 4)));
        }
        if (t < 31) { ST_A(buf ^ 1, 1, kb1); ST_A(buf ^ 1, 3, kb1); }
        WAIT_MFMA_ENTER();
        #pragma unroll
        for (int i = 0; i < 4; ++i)
            #pragma unroll
            for (int nj = 0; nj < 2; ++nj)
                #pragma unroll
                for (int k = 0; k < 2; ++k)
                    acc[4 + i][nj] = MFMA16(af[i][k], b01[nj][k], acc[4 + i][nj]);
        __builtin_amdgcn_s_setprio(0);
        __builtin_amdgcn_s_barrier();

        // ---- P3: MFMA (MH1, nj2) from regs; boundary vmcnt(2)
        __builtin_amdgcn_s_setprio(1);
        #pragma unroll
        for (int i = 0; i < 4; ++i)
            #pragma unroll
            for (int k = 0; k < 2; ++k)
                acc[4 + i][2] = MFMA16(af[i][k], b2[k], acc[4 + i][2]);
        __builtin_amdgcn_s_setprio(0);
        if (t < 31) { asm volatile("s_waitcnt vmcnt(2)" ::: "memory"); }
        __builtin_amdgcn_s_barrier();
    }

    // ---- epilogue: n may straddle tensor boundaries (192 ∤ 2048)
    #pragma unroll
    for (int mi = 0; mi < 8; ++mi) {
        #pragma unroll
        for (int nj = 0; nj < 3; ++nj) {
            const int nbase = n0 + wn * 48 + nj * 16;
            const int t0 = nbase >> 11, t1 = (nbase + 15) >> 11;
            const int m_r0 = m0 + wm * 128 + mi * 16 + 4 * g;
            const int bb = m_r0 >> 11;
            if (t0 == 2 && t1 == 2) {
                // pure V frag: packed over r, transposed store (b,h,d,s)
                const int n = nbase + c, d = n & (DK_ - 1), h = (n >> 7) & 15;
                const int s0 = m_r0 & (S_ - 1);
                __hip_bfloat16 ob[4];
                #pragma unroll
                for (int r = 0; r < 4; ++r) ob[r] = __float2bfloat16(acc[mi][nj][r]);
                ushort4 u; __builtin_memcpy(&u, ob, 8);
                size_t a = ((size_t)(bb * 16 + h) * DK_ + d) * S_ + s0;
                *(ushort4*)(Vo + a) = u;
            } else if (t1 < 2) {
                // pure Q or K frag: RoPE
                __hip_bfloat16* Cq = (t0 == 0) ? Qo : Ko;
                const int n = nbase + c, d = n & (DK_ - 1), h = (n >> 7) & 15;
                #pragma unroll
                for (int r = 0; r < 4; ++r) {
                    float v = acc[mi][nj][r];
                    float vp = __shfl_xor(v, 1);
                    int srow = (m_r0 + r) & (S_ - 1);
                    float cs = CT[srow * 64 + (d >> 1)];
                    float sn = ST[srow * 64 + (d >> 1)];
                    float o = (c & 1) ? __builtin_fmaf(v, cs, vp * sn)
                                      : __builtin_fmaf(v, cs, -vp * sn);
                    size_t a = ((size_t)(bb * 16 + h) * S_ + srow) * DK_ + d;
                    Cq[a] = __float2bfloat16(o);
                }
            } else {
                // straddling frag: per-element
                const int n = nbase + c, tens = n >> 11;
                const int rn = n & 2047, d = rn & (DK_ - 1), h = rn >> 7;
                #pragma unroll
                for (int r = 0; r < 4; ++r) {
                    float v = acc[mi][nj][r];
                    float vp = __shfl_xor(v, 1);   // all lanes execute
                    int srow = (m_r0 + r) & (S_ - 1);
                    if (tens == 2) {
                        size_t a = ((size_t)(bb * 16 + h) * DK_ + d) * S_ + srow;
                        Vo[a] = __float2bfloat16(v);
                    } else {
                        __hip_bfloat16* Cq = (tens == 0) ? Qo : Ko;
                        float cs = CT[srow * 64 + (d >> 1)];
                        float sn = ST[srow * 64 + (d >> 1)];
                        float o = (c & 1) ? __builtin_fmaf(v, cs, vp * sn)
                                          : __builtin_fmaf(v, cs, -vp * sn);
                        size_t a = ((size_t)(bb * 16 + h) * S_ + srow) * DK_ + d;
                        Cq[a] = __float2bfloat16(o);
                    }
                }
            }
        }
    }
}

// ---------------- out-projection GEMM (f32 out), 128x128 2-phase ----------------
__global__ __launch_bounds__(256, 2)
void gemm_out(const __hip_bfloat16* __restrict__ A, const __hip_bfloat16* __restrict__ W,
              float* __restrict__ Cout, int M, int N, int K)
{
    __shared__ __align__(16) __hip_bfloat16 As[128 * 64];
    __shared__ __align__(16) __hip_bfloat16 Bs[128 * 64];
    const int tid = threadIdx.x;
    const int lane = tid & 63, wv = tid >> 6;
    const int wr = wv >> 1, wc = wv & 1;
    const int m0 = blockIdx.x * 128, n0 = blockIdx.y * 128;
    const int g = lane >> 4, c = lane & 15;

    f32x4 acc[4][4];
    #pragma unroll
    for (int i = 0; i < 4; ++i)
        #pragma unroll
        for (int j = 0; j < 4; ++j) acc[i][j] = f32x4{0.f, 0.f, 0.f, 0.f};

    for (int k0 = 0; k0 < K; k0 += 64) {
        __syncthreads();
        #pragma unroll
        for (int it = 0; it < 4; ++it) {
            int o = (it * 256 + tid) * 16;
            int row = o >> 7;
            int colb = (o ^ ((row & 7) << 4)) & 127;
            GLD16((const char*)(A + (size_t)(m0 + row) * K + k0) + colb, (char*)As + o);
            GLD16((const char*)(W + (size_t)(n0 + row) * K + k0) + colb, (char*)Bs + o);
        }
        __syncthreads();
        #pragma unroll
        for (int ks = 0; ks < 2; ++ks) {
            bf16x8 af[4], bfm[4];
            #pragma unroll
            for (int i = 0; i < 4; ++i) {
                int arow = wr * 64 + i * 16 + c;
                int ab = arow * 128 + ((ks * 64 + g * 16) ^ ((arow & 7) << 4));
                af[i] = *(const bf16x8*)((const char*)As + ab);
                int brow = wc * 64 + i * 16 + c;
                int bb = brow * 128 + ((ks * 64 + g * 16) ^ ((brow & 7) << 4));
                bfm[i] = *(const bf16x8*)((const char*)Bs + bb);
            }
            #pragma unroll
            for (int i = 0; i < 4; ++i)
                #pragma unroll
                for (int j = 0; j < 4; ++j)
                    acc[i][j] = MFMA16(af[i], bfm[j], acc[i][j]);
        }
    }

    #pragma unroll
    for (int i = 0; i < 4; ++i)
        #pragma unroll
        for (int j = 0; j < 4; ++j)
            #pragma unroll
            for (int r = 0; r < 4; ++r) {
                int m = m0 + wr * 64 + i * 16 + 4 * g + r;
                int n = n0 + wc * 64 + j * 16 + c;
                Cout[(size_t)m * N + n] = acc[i][j][r];
            }
}

// ---------------- flash attention (causal), XCD-swizzled + balanced pairs ---------
__device__ __forceinline__ void stage_kv(const __hip_bfloat16* Kp, const __hip_bfloat16* Vp,
                                         char* ks, char* vs, int kv0, int tid) {
    #pragma unroll
    for (int it = 0; it < 4; ++it) {
        int o = (it * 256 + tid) * 16;
        int row = o >> 8;
        int cb = (o ^ ((row & 7) << 4)) & 255;
        GLD16((const char*)(Kp + (size_t)(kv0 + row) * DK_) + cb, ks + o);
    }
    #pragma unroll
    for (int it = 0; it < 4; ++it) {
        int o = (it * 256 + tid) * 16;
        int row = o >> 7;
        int cb = (o ^ ((row & 7) << 4)) & 127;
        GLD16((const char*)(Vp + (size_t)row * S_ + kv0) + cb, vs + o);
    }
}

__global__ __launch_bounds__(256, 2)
void attn_kernel(const __hip_bfloat16* __restrict__ Q,
                 const __hip_bfloat16* __restrict__ Kt,
                 const __hip_bfloat16* __restrict__ VT,
                 __hip_bfloat16* __restrict__ O)
{
    __shared__ __align__(16) __hip_bfloat16 Ks[2][64 * 128];
    __shared__ __align__(16) __hip_bfloat16 Vs[2][128 * 64];
    __shared__ __align__(16) __hip_bfloat16 Ps[4][16 * 72];

    const int tid = threadIdx.x, lane = tid & 63, w = tid >> 6;
    const int g = lane >> 4, c = lane & 15;
    const int id = blockIdx.x;
    const int slot = id & 7, jj = id >> 3;
    const int bh = ((jj >> 4) << 3) | slot;
    const int xq = jj & 15;
    const int b = bh >> 4, h = bh & 15;
    const size_t base_bh = (size_t)bh * S_ * DK_;
    const __hip_bfloat16* Qp = Q + base_bh;
    const __hip_bfloat16* Kp = Kt + base_bh;
    const __hip_bfloat16* Vp = VT + base_bh;

    #pragma unroll 1
    for (int pass = 0; pass < 2; ++pass) {
        const int qt = pass ? (31 - xq) : xq;
        const int qw = qt * 64 + w * 16;
        const int ntiles = qt + 1;

        bf16x8 qf[4];
        #pragma unroll
        for (int ds = 0; ds < 4; ++ds)
            qf[ds] = *(const bf16x8*)(Qp + (size_t)(qw + c) * DK_ + ds * 32 + g * 8);

        f32x4 oacc[8];
        #pragma unroll
        for (int fd = 0; fd < 8; ++fd) oacc[fd] = f32x4{0.f, 0.f, 0.f, 0.f};
        float M[4], L[4];
        #pragma unroll
        for (int r = 0; r < 4; ++r) { M[r] = -1e30f; L[r] = 0.f; }

        stage_kv(Kp, Vp, (char*)Ks[0], (char*)Vs[0], 0, tid);
        __syncthreads();

        int cur = 0;
        for (int t = 0; t < ntiles; ++t) {
            const int kv0 = t * 64;
            if (t + 1 < ntiles)
                stage_kv(Kp, Vp, (char*)Ks[cur ^ 1], (char*)Vs[cur ^ 1], kv0 + 64, tid);

            const bool diag = (kv0 + 63 > qw);

            f32x4 sacc[4];
            #pragma unroll
            for (int f = 0; f < 4; ++f) sacc[f] = f32x4{0.f, 0.f, 0.f, 0.f};
            #pragma unroll
            for (int f = 0; f < 4; ++f) {
                #pragma unroll
                for (int ds = 0; ds < 4; ++ds) {
                    int krow = f * 16 + c;
                    int kbyt = krow * 256 + ((ds * 64 + g * 16) ^ ((krow & 7) << 4));
                    bf16x8 kf = *(const bf16x8*)((const char*)Ks[cur] + kbyt);
                    sacc[f] = MFMA16(qf[ds], kf, sacc[f]);
                }
            }

            float p[4][4];
            float mt[4] = {-1e30f, -1e30f, -1e30f, -1e30f};
            #pragma unroll
            for (int f = 0; f < 4; ++f)
                #pragma unroll
                for (int r = 0; r < 4; ++r) {
                    float v = sacc[f][r];
                    if (diag && (kv0 + f * 16 + c > qw + 4 * g + r)) v = -1e30f;
                    p[f][r] = v;
                    mt[r] = fmaxf(mt[r], v);
                }
            #pragma unroll
            for (int r = 0; r < 4; ++r) {
                float v = mt[r];
                v = fmaxf(v, __shfl_xor(v, 1));
                v = fmaxf(v, __shfl_xor(v, 2));
                v = fmaxf(v, __shfl_xor(v, 4));
                v = fmaxf(v, __shfl_xor(v, 8));
                mt[r] = v;
            }
            bool grow = (mt[0] > M[0] + THR_RAW_) || (mt[1] > M[1] + THR_RAW_) ||
                        (mt[2] > M[2] + THR_RAW_) || (mt[3] > M[3] + THR_RAW_);
            if (__any(grow)) {
                float al[4];
                #pragma unroll
                for (int r = 0; r < 4; ++r) {
                    float mn = fmaxf(M[r], mt[r]);
                    al[r] = __expf((M[r] - mn) * SCALE_);
                    M[r] = mn;
                    L[r] *= al[r];
                }
                #pragma unroll
                for (int fd = 0; fd < 8; ++fd)
                    #pragma unroll
                    for (int r = 0; r < 4; ++r) oacc[fd][r] *= al[r];
            }
            float ms[4];
            #pragma unroll
            for (int r = 0; r < 4; ++r) ms[r] = M[r] * SCALE_;
            float lt[4] = {0.f, 0.f, 0.f, 0.f};
            #pragma unroll
            for (int f = 0; f < 4; ++f)
                #pragma unroll
                for (int r = 0; r < 4; ++r) {
                    float e = __expf(__builtin_fmaf(p[f][r], SCALE_, -ms[r]));
                    lt[r] += e;
                    Ps[w][(4 * g + r) * 72 + f * 16 + c] = __float2bfloat16(e);
                }
            #pragma unroll
            for (int r = 0; r < 4; ++r) {
                float v = lt[r];
                v += __shfl_xor(v, 1);
                v += __shfl_xor(v, 2);
                v += __shfl_xor(v, 4);
                v += __shfl_xor(v, 8);
                L[r] += v;
            }

            #pragma unroll
            for (int ks2 = 0; ks2 < 2; ++ks2) {
                bf16x8 pf = *(const bf16x8*)&Ps[w][c * 72 + ks2 * 32 + g * 8];
                #pragma unroll
                for (int fd = 0; fd < 8; ++fd) {
                    int vrow = fd * 16 + c;
                    int vb = vrow * 128 + ((ks2 * 64 + g * 16) ^ ((vrow & 7) << 4));
                    bf16x8 vf = *(const bf16x8*)((const char*)Vs[cur] + vb);
                    oacc[fd] = MFMA16(pf, vf, oacc[fd]);
                }
            }
            __syncthreads();
            cur ^= 1;
        }

        float rl[4];
        #pragma unroll
        for (int r = 0; r < 4; ++r) rl[r] = 1.0f / L[r];
        #pragma unroll
        for (int fd = 0; fd < 8; ++fd) {
            #pragma unroll
            for (int r = 0; r < 4; ++r) {
                int s = qw + 4 * g + r;
                size_t a = ((size_t)(b * S_ + s)) * (H_ * DK_) + h * DK_ + fd * 16 + c;
                O[a] = __float2bfloat16(oacc[fd][r] * rl[r]);
            }
        }
    }
}

extern "C" void kernel_launch(void* const* d_in, const int* in_sizes, int n_in,
                              void* d_out, int out_size, void* d_ws, size_t ws_size,
                              hipStream_t stream) {
    const float* x  = (const float*)d_in[0];
    const float* wq = (const float*)d_in[1];
    const float* wk = (const float*)d_in[2];
    const float* wv = (const float*)d_in[3];
    const float* wo = (const float*)d_in[4];
    const float* pe = (const float*)d_in[5];
    float* out = (float*)d_out;

    const size_t XE = (size_t)B_ * S_ * E_;   // 8388608
    const size_t WE = (size_t)E_ * H_ * DK_;  // 4194304
    __hip_bfloat16* xb  = (__hip_bfloat16*)d_ws;
    __hip_bfloat16* wqb = xb + XE;            // wq|wk|wv contiguous = 6144x2048
    __hip_bfloat16* wkb = wqb + WE;
    __hip_bfloat16* wvb = wkb + WE;
    __hip_bfloat16* wob = wvb + WE;
    __hip_bfloat16* qb  = wob + WE;  // (B,H,S,DK)
    __hip_bfloat16* kb  = qb + XE;   // (B,H,S,DK)
    __hip_bfloat16* vT  = kb + XE;   // (B,H,DK,S)
    __hip_bfloat16* at  = vT + XE;   // (B*S, H*DK)
    float* ct = (float*)(at + XE);
    float* st = ct + (size_t)S_ * 64;

    cast_f32_bf16<<<dim3((int)(XE / 4 / 256)), 256, 0, stream>>>(x, xb, (int)(XE / 4));
    cast_w4<<<dim3((int)(WE / 4 / 256), 4), 256, 0, stream>>>(wq, wk, wv, wo,
                                                              wqb, wkb, wvb, wob,
                                                              (int)(WE / 4));
    trig_table<<<dim3(S_ * 64 / 256), 256, 0, stream>>>(pe, ct, st);

    gemm_qkv8<<<dim3(512), 512, 0, stream>>>(xb, wqb, qb, kb, vT, ct, st);

    attn_kernel<<<dim3(512), 256, 0, stream>>>(qb, kb, vT, at);

    gemm_out<<<dim3(32, 16), 256, 0, stream>>>(at, wob, out, B_ * S_, E_, H_ * DK_);
}